// Round 1
// 152.970 us; speedup vs baseline: 1.1764x; 1.1764x over previous
//
#include <hip/hip_runtime.h>
#include <hip/hip_bf16.h>

// PNALayer: B=4, Nc=512, Nf=256, F_NHID=C_NHID=64, U_HID=U_OUT=128, M_INIT=1600, M_HID=256, M_OUT=64
// ALL I/O float32. R18 = R17 (180us) + edge rewrite: col-split waves, B-frags in VGPRs (bf16 W2T
// precomputed in prep1), cvt_pk bf16 packing, LDS 64000->20480 B, launch_bounds(256,4).

using bs8 = __attribute__((ext_vector_type(8))) short;   // 8 bf16 in 4 VGPRs (MFMA A/B frag)
using f4  = __attribute__((ext_vector_type(4))) float;   // MFMA C/D frag

__device__ __forceinline__ unsigned short f2bf(float f) {
    union { float f; unsigned int u; } x; x.f = f;
    unsigned int u = x.u + 0x7FFFu + ((x.u >> 16) & 1u);
    return (unsigned short)(u >> 16);
}

// packed pair via v_cvt_pk_bf16_f32 (compiler emits it from the _rn intrinsic)
__device__ __forceinline__ unsigned int pkbf(float a, float b) {
    __hip_bfloat162 h = __float22bfloat162_rn(make_float2(a, b));
    union { __hip_bfloat162 h; unsigned int u; } c; c.h = h;
    return c.u;
}

// Stub-parity symbol (harmless).
__global__ void PNALayer_35081292874189_kernel() {}

// ---------------- workspace layout (bytes) ----------------
#define OFF_AC     0u          // 2048*128 f32 = 1048576
#define OFF_AF     1048576u    // 1024*128 f32 = 524288
#define OFF_DEGC   1572864u    // 2048 f32
#define OFF_DEGF   1581056u    // 1024 f32
#define OFF_SCALE  1585152u    // 2048 f32
#define OFF_SINV   1593344u    // 2048 f32
#define OFF_FEATB  1601536u    // 2048*1600 bf16 = 6553600 (+256 slack for K-pad overread)
#define OFF_HMID   8155392u    // 2048*256 f32   = 2097152
#define OFF_W2T    10252544u   // 128*128 bf16   = 32768 (U_W2^T, n-major, bf16)
#define OFF_W1TB   10318080u   // 256*1664 bf16  = 851968 (M_W1^T, n-major, K zero-padded to 1664)
#define WS_NEED    11170048u

__global__ void PNALayer_ws_fail(float* out, int n) {
    int i = blockIdx.x * 256 + threadIdx.x;
    if (i < n) out[i] = 2500.0f;
}

// K1: A_c, A_f, degrees, U_W2 transpose->bf16 (4 blocks), M_W1 transpose->bf16 (100 blocks), pad (1)
__global__ void PNALayer_prep1(
    const float* h_fac, const float* h_cus, const float* adj,
    const float* U_W1, const float* U_b1, const float* U_W2, const float* M_W1,
    float* wsAc, float* wsAf, float* wsDegC, float* wsDegF,
    unsigned short* wsW2Tb, unsigned short* wsW1Tb)
{
    __shared__ float sH[64];
    __shared__ float sRed[256];
    __shared__ float sT[64][65];
    int bid = blockIdx.x, t = threadIdx.x;

    if (bid < 1024) {
        int b = bid >> 8, f = bid & 255;
        if (t < 64) sH[t] = h_fac[(b * 256 + f) * 64 + t];
        __syncthreads();
        if (t < 128) {
            float acc = 0.f;
            for (int k = 0; k < 64; ++k)
                acc += sH[k] * U_W1[(64 + k) * 128 + t];
            wsAf[(b * 256 + f) * 128 + t] = acc;
        }
        float v = adj[(b * 512 + t) * 256 + f] + adj[(b * 512 + t + 256) * 256 + f];
        sRed[t] = v; __syncthreads();
        for (int s = 128; s > 0; s >>= 1) { if (t < s) sRed[t] += sRed[t + s]; __syncthreads(); }
        if (t == 0) wsDegF[b * 256 + f] = sRed[0];
    } else if (bid < 3072) {
        int bc = bid - 1024;
        if (t < 64) sH[t] = h_cus[bc * 64 + t];
        __syncthreads();
        if (t < 128) {
            float acc = U_b1[t];
            for (int k = 0; k < 64; ++k)
                acc += sH[k] * U_W1[k * 128 + t];
            wsAc[bc * 128 + t] = acc;
        }
        float v = adj[bc * 256 + t];
        sRed[t] = v; __syncthreads();
        for (int s = 128; s > 0; s >>= 1) { if (t < s) sRed[t] += sRed[t + s]; __syncthreads(); }
        if (t == 0) wsDegC[bc] = sRed[0];
    } else if (bid < 3076) {
        // transpose U_W2 [k][n] -> wsW2Tb [n][k] bf16, 64x64 tiles
        int l = bid - 3072;
        int k0 = (l >> 1) * 64, n0 = (l & 1) * 64;
        for (int rep = 0; rep < 16; ++rep) {
            int idx = rep * 256 + t; int r = idx >> 6, c = idx & 63;
            sT[r][c] = U_W2[(k0 + r) * 128 + n0 + c];
        }
        __syncthreads();
        for (int rep = 0; rep < 16; ++rep) {
            int idx = rep * 256 + t; int r = idx >> 6, c = idx & 63;
            wsW2Tb[(n0 + r) * 128 + k0 + c] = f2bf(sT[c][r]);
        }
    } else if (bid < 3176) {
        // transpose M_W1 [k][n] (1600x256) -> wsW1Tb [n][k] bf16, 64x64 tiles
        int l = bid - 3076;            // 0..99
        int k0 = (l % 25) * 64, n0 = (l / 25) * 64;
        for (int rep = 0; rep < 16; ++rep) {
            int idx = rep * 256 + t; int r = idx >> 6, c = idx & 63;
            sT[r][c] = M_W1[(k0 + r) * 256 + n0 + c];
        }
        __syncthreads();
        for (int rep = 0; rep < 16; ++rep) {
            int idx = rep * 256 + t; int r = idx >> 6, c = idx & 63;
            wsW1Tb[(n0 + r) * 1664 + k0 + c] = f2bf(sT[c][r]);
        }
    } else {
        // zero the K-pad region k in [1600,1664) for all 256 n
        for (int i = 0; i < 64; ++i) {
            int idx = i * 256 + t;     // 0..16383
            int n = idx >> 6, k = 1600 + (idx & 63);
            wsW1Tb[n * 1664 + k] = 0;
        }
    }
}

// K2: avg_d, scale, scale_inv per batch
__global__ void PNALayer_prep2(
    const float* wsDegC, const float* wsDegF, float* wsScale, float* wsSinv)
{
    __shared__ float sRed[256];
    __shared__ float sAvg;
    int b = blockIdx.x, t = threadIdx.x;
    float v = logf(wsDegC[b * 512 + t] + 1.f) + logf(wsDegC[b * 512 + t + 256] + 1.f)
            + logf(wsDegF[b * 256 + t] + 1.f);
    sRed[t] = v; __syncthreads();
    for (int s = 128; s > 0; s >>= 1) { if (t < s) sRed[t] += sRed[t + s]; __syncthreads(); }
    if (t == 0) sAvg = sRed[0] / 768.f;
    __syncthreads();
    float avg = sAvg;
    for (int c = t; c < 512; c += 256) {
        float lg = logf(wsDegC[b * 512 + c] + 1.f);
        float sc = lg / avg;
        float si = (sc != 0.f) ? 1.f / sc : 0.f;
        wsScale[b * 512 + c] = sc;
        wsSinv[b * 512 + c] = si;
    }
}

// K3: per-(b,c) edge MLP via MFMA + masked aggregation -> featB row (1600, bf16)
// Col-split waves: wave w owns output cols [w*32, w*32+32); B-frags live in 32 VGPRs
// (loaded once from L2-resident bf16 W2T). No sW2T, no sRed, no zero-memset.
// LDS: sM1 64x136 bf16 = 17408 + sE/sMk 2048 + sAc/sWe 1024 = 20480 B -> 4 blocks/CU.
__global__ __launch_bounds__(256, 4) void PNALayer_edge(
    const float* h_cus, const float* edge, const float* adj,
    const float* U_W1, const float* U_b2,
    const float* wsAc, const float* wsAf, const unsigned short* wsW2Tb,
    const float* wsDegC, const float* wsScale, const float* wsSinv,
    unsigned short* featB)
{
    __shared__ __align__(16) unsigned short sM1[64 * 136];
    __shared__ float sE[256];
    __shared__ float sMk[256];
    __shared__ float sAc[128];
    __shared__ float sWe[128];

    int bc = blockIdx.x;
    int b  = bc >> 9;
    int t  = threadIdx.x;
    int w = t >> 6, quad = (t >> 4) & 3, ln = t & 15;

    // B fragments for this wave's two 16-col tiles, loaded once (global, L2-hit).
    int r0 = (w * 2 + 0) * 16 + ln;
    int r1 = (w * 2 + 1) * 16 + ln;
    bs8 bw0[4], bw1[4];
#pragma unroll
    for (int kk = 0; kk < 4; ++kk) {
        bw0[kk] = *(const bs8*)(wsW2Tb + r0 * 128 + kk * 32 + quad * 8);
        bw1[kk] = *(const bs8*)(wsW2Tb + r1 * 128 + kk * 32 + quad * 8);
    }
    float b2v0 = U_b2[r0], b2v1 = U_b2[r1];

    sE[t]  = edge[bc * 256 + t];
    sMk[t] = (adj[bc * 256 + t] > 0.f) ? 1.f : 0.f;
    if (t < 128) {
        sAc[t] = wsAc[bc * 128 + t];
        sWe[t] = U_W1[128 * 128 + t];
    }
    if (t < 64) featB[bc * 1600 + t] = f2bf(h_cus[bc * 64 + t]);
    __syncthreads();

    float aS[2]  = {0.f, 0.f},     aQ[2]  = {0.f, 0.f};
    float aMx[2] = {-1e30f, -1e30f}, aMn[2] = {1e30f, 1e30f};

    for (int ft = 0; ft < 4; ++ft) {
        // stage: relu(A_c + A_f + e*We) -> bf16 sM1 (64 edges x 128 dims)
#pragma unroll
        for (int i = 0; i < 8; ++i) {
            int idx = i * 256 + t;
            int fl = idx >> 5, k = (idx & 31) * 4;
            int f = ft * 64 + fl;
            float4 af  = *(const float4*)(wsAf + (b * 256 + f) * 128 + k);
            float4 ac4 = *(const float4*)(sAc + k);
            float4 we4 = *(const float4*)(sWe + k);
            float e = sE[f];
            float m0 = fmaxf(ac4.x + af.x + e * we4.x, 0.f);
            float m1 = fmaxf(ac4.y + af.y + e * we4.y, 0.f);
            float m2 = fmaxf(ac4.z + af.z + e * we4.z, 0.f);
            float m3 = fmaxf(ac4.w + af.w + e * we4.w, 0.f);
            uint2 p;
            p.x = pkbf(m0, m1);
            p.y = pkbf(m2, m3);
            *(uint2*)(sM1 + fl * 136 + k) = p;
        }
        __syncthreads();

        f4 acc[4][2];
#pragma unroll
        for (int rt = 0; rt < 4; ++rt) {
            acc[rt][0] = (f4){0.f, 0.f, 0.f, 0.f};
            acc[rt][1] = (f4){0.f, 0.f, 0.f, 0.f};
        }
#pragma unroll
        for (int kk = 0; kk < 4; ++kk) {
            int ko = kk * 32 + quad * 8;
#pragma unroll
            for (int rt = 0; rt < 4; ++rt) {
                bs8 a = *(const bs8*)(sM1 + (rt * 16 + ln) * 136 + ko);
                acc[rt][0] = __builtin_amdgcn_mfma_f32_16x16x32_bf16(a, bw0[kk], acc[rt][0], 0, 0, 0);
                acc[rt][1] = __builtin_amdgcn_mfma_f32_16x16x32_bf16(a, bw1[kk], acc[rt][1], 0, 0, 0);
            }
        }

        // masked aggregation (registers + read-only sMk)
#pragma unroll
        for (int rt = 0; rt < 4; ++rt) {
#pragma unroll
            for (int i = 0; i < 4; ++i) {
                int f = ft * 64 + rt * 16 + quad * 4 + i;
                if (sMk[f] > 0.f) {
                    float v0 = acc[rt][0][i] + b2v0;
                    float v1 = acc[rt][1][i] + b2v1;
                    aS[0] += v0; aQ[0] += v0 * v0;
                    aMx[0] = fmaxf(aMx[0], v0); aMn[0] = fminf(aMn[0], v0);
                    aS[1] += v1; aQ[1] += v1 * v1;
                    aMx[1] = fmaxf(aMx[1], v1); aMn[1] = fminf(aMn[1], v1);
                }
            }
        }
        __syncthreads();
    }

    // finish reduction across the 4 quads (rows live on lanes quad*16+ln)
#pragma unroll
    for (int nt = 0; nt < 2; ++nt) {
        aS[nt]  += __shfl_xor(aS[nt], 16, 64);  aS[nt]  += __shfl_xor(aS[nt], 32, 64);
        aQ[nt]  += __shfl_xor(aQ[nt], 16, 64);  aQ[nt]  += __shfl_xor(aQ[nt], 32, 64);
        aMx[nt] = fmaxf(aMx[nt], __shfl_xor(aMx[nt], 16, 64));
        aMx[nt] = fmaxf(aMx[nt], __shfl_xor(aMx[nt], 32, 64));
        aMn[nt] = fminf(aMn[nt], __shfl_xor(aMn[nt], 16, 64));
        aMn[nt] = fminf(aMn[nt], __shfl_xor(aMn[nt], 32, 64));
    }

    if (quad == 0) {
        float cnt = wsDegC[bc];
        float sc = wsScale[bc], si = wsSinv[bc];
        unsigned short* fr = featB + bc * 1600;
#pragma unroll
        for (int nt = 0; nt < 2; ++nt) {
            int col = (w * 2 + nt) * 16 + ln;
            float mean = aS[nt] / cnt;
            float var  = fmaxf(aQ[nt] / cnt - mean * mean, 0.f);
            float stdv = sqrtf(var);
            float mx = aMx[nt], mn = aMn[nt];
            fr[64 + col]   = f2bf(mean); fr[192 + col]  = f2bf(mean * sc); fr[320 + col]  = f2bf(mean * si);
            fr[448 + col]  = f2bf(stdv); fr[576 + col]  = f2bf(stdv * sc); fr[704 + col]  = f2bf(stdv * si);
            fr[832 + col]  = f2bf(mx);   fr[960 + col]  = f2bf(mx * sc);   fr[1088 + col] = f2bf(mx * si);
            fr[1216 + col] = f2bf(mn);   fr[1344 + col] = f2bf(mn * sc);   fr[1472 + col] = f2bf(mn * si);
        }
    }
}

// K4: h_mid = relu(featB @ W1Tb^T + b1) via MFMA. Block = 16 rows x 64 cols, grid 512.
// LDS: sA bf16[16][136]=4352B, sB bf16[64][136]=17408B  (21760 B total)
__global__ __launch_bounds__(256) void PNALayer_mlp1(
    const unsigned short* featB, const unsigned short* wsW1Tb, const float* M_b1,
    float* h_mid)
{
    __shared__ __align__(16) unsigned short sA[16 * 136];
    __shared__ __align__(16) unsigned short sB[64 * 136];
    int t = threadIdx.x;
    int rb = (blockIdx.x >> 2) * 16, cb = (blockIdx.x & 3) * 64;
    int w = t >> 6, quad = (t >> 4) & 3, ln = t & 15;

    f4 acc = (f4){0.f, 0.f, 0.f, 0.f};

    for (int kt = 0; kt < 13; ++kt) {
        int kb = kt * 128;
        {   // stage A: 16 rows x 128 k (256 uint4, 1/thread)
            int row = t >> 4, c8 = (t & 15) * 8;
            *(uint4*)(sA + row * 136 + c8) =
                *(const uint4*)(featB + (rb + row) * 1600 + kb + c8);
        }
        for (int i = 0; i < 4; ++i) {   // stage B: 64 n-rows x 128 k (1024 uint4)
            int vi = i * 256 + t;
            int row = vi >> 4, c8 = (vi & 15) * 8;
            *(uint4*)(sB + row * 136 + c8) =
                *(const uint4*)(wsW1Tb + (cb + row) * 1664 + kb + c8);
        }
        __syncthreads();
        for (int kk = 0; kk < 4; ++kk) {
            int ko = kk * 32 + quad * 8;
            bs8 a = *(const bs8*)(sA + ln * 136 + ko);
            bs8 bb = *(const bs8*)(sB + (w * 16 + ln) * 136 + ko);
            acc = __builtin_amdgcn_mfma_f32_16x16x32_bf16(a, bb, acc, 0, 0, 0);
        }
        __syncthreads();
    }
    // C/D: col=ln (n), row=quad*4+i (m)
    int col = cb + w * 16 + ln;
    float b1v = M_b1[col];
    for (int i = 0; i < 4; ++i) {
        int row = rb + quad * 4 + i;
        h_mid[row * 256 + col] = fmaxf(acc[i] + b1v, 0.f);
    }
}

// K5: out = h_mid @ M_W2 + b2  (f32)
__global__ void PNALayer_mlp2(
    const float* h_mid, const float* M_W2, const float* M_b2, float* out)
{
    int idx = blockIdx.x * 256 + threadIdx.x;   // [0, 131072)
    int row = idx >> 6, j = idx & 63;
    float acc = M_b2[j];
    const float* hr = h_mid + row * 256;
    for (int k = 0; k < 256; ++k)
        acc += hr[k] * M_W2[k * 64 + j];
    out[idx] = acc;
}

extern "C" void kernel_launch(void* const* d_in, const int* in_sizes, int n_in,
                              void* d_out, int out_size, void* d_ws, size_t ws_size,
                              hipStream_t stream) {
    const float* h_fac = (const float*)d_in[0];
    const float* h_cus = (const float*)d_in[1];
    const float* edge  = (const float*)d_in[2];
    const float* adj   = (const float*)d_in[3];
    const float* U_W1  = (const float*)d_in[4];
    const float* U_b1  = (const float*)d_in[5];
    const float* U_W2  = (const float*)d_in[6];
    const float* U_b2  = (const float*)d_in[7];
    const float* M_W1  = (const float*)d_in[8];
    const float* M_b1  = (const float*)d_in[9];
    const float* M_W2  = (const float*)d_in[10];
    const float* M_b2  = (const float*)d_in[11];
    (void)in_sizes; (void)n_in;

    float* outp = (float*)d_out;
    int nblk_out = (out_size + 255) / 256;

    if (ws_size < (size_t)WS_NEED) {
        PNALayer_ws_fail<<<nblk_out, 256, 0, stream>>>(outp, out_size);
        return;
    }

    char* ws = (char*)d_ws;
    float*          wsAc   = (float*)(ws + OFF_AC);
    float*          wsAf   = (float*)(ws + OFF_AF);
    float*          wsDegC = (float*)(ws + OFF_DEGC);
    float*          wsDegF = (float*)(ws + OFF_DEGF);
    float*          wsScal = (float*)(ws + OFF_SCALE);
    float*          wsSinv = (float*)(ws + OFF_SINV);
    unsigned short* wsFeatB= (unsigned short*)(ws + OFF_FEATB);
    float*          wsHmid = (float*)(ws + OFF_HMID);
    unsigned short* wsW2Tb = (unsigned short*)(ws + OFF_W2T);
    unsigned short* wsW1Tb = (unsigned short*)(ws + OFF_W1TB);

    PNALayer_prep1<<<3177, 256, 0, stream>>>(
        h_fac, h_cus, adj, U_W1, U_b1, U_W2, M_W1,
        wsAc, wsAf, wsDegC, wsDegF, wsW2Tb, wsW1Tb);
    PNALayer_prep2<<<4, 256, 0, stream>>>(wsDegC, wsDegF, wsScal, wsSinv);
    PNALayer_edge<<<2048, 256, 0, stream>>>(
        h_cus, edge, adj, U_W1, U_b2,
        wsAc, wsAf, wsW2Tb, wsDegC, wsScal, wsSinv, wsFeatB);
    PNALayer_mlp1<<<512, 256, 0, stream>>>(wsFeatB, wsW1Tb, M_b1, wsHmid);
    PNALayer_mlp2<<<512, 256, 0, stream>>>(wsHmid, M_W2, M_b2, outp);
}